// Round 8
// baseline (176.056 us; speedup 1.0000x reference)
//
#include <hip/hip_runtime.h>
#include <stdint.h>

#define N_  32
#define C_  128
#define H_  56
#define W_  56
#define HW_ 3136
#define P_  128

using i32x4  = __attribute__((ext_vector_type(4)))  int;
using i32x16 = __attribute__((ext_vector_type(16))) int;

// ws layout (bytes):
//   wI8 : P*1152 = 147,456  (i8 +1/-1 weights, [p][tap*128+c])
//   inv : P*4
//   b0  : P*4
#define WI8_BYTES (P_*1152)

// ------- pack weights to i8 +1/-1 in [p][t*128+c] layout; fold BN ------------
__global__ __launch_bounds__(256) void wpack_kernel(const float* __restrict__ weight,
        const float* __restrict__ bias, const float* __restrict__ gamma,
        const float* __restrict__ beta, const float* __restrict__ mean,
        const float* __restrict__ var,
        uint32_t* __restrict__ wI8, float* __restrict__ invG, float* __restrict__ b0G) {
    int gid = blockIdx.x * 256 + threadIdx.x;        // 144 blocks = 36864 dwords
    int p   = gid / 288;
    int rem = gid % 288;
    int k   = rem * 4;                               // k = t*128 + c
    int tp  = k >> 7;
    int c   = k & 127;
    uint32_t d = 0;
    #pragma unroll
    for (int i2 = 0; i2 < 4; ++i2) {
        float v = weight[((size_t)p * C_ + c + i2) * 9 + tp];
        uint32_t by = (v >= 0.f) ? 0x01u : 0xFFu;
        d |= by << (8 * i2);
    }
    wI8[gid] = d;
    if (blockIdx.x == 0 && threadIdx.x < P_) {
        int pp = threadIdx.x;
        float inv = gamma[pp] * rsqrtf(var[pp] + 1e-5f);
        invG[pp] = inv;
        b0G[pp]  = bias[pp] * inv + beta[pp] - mean[pp] * inv;
    }
}

// ------- fused: sign-binarize x in-kernel + binary conv via i8 MFMA + BN + res
// Block: 2 output rows x 64 cols x 128 out-ch. R8: main loop switched to
// v_mfma_i32_32x32x32_i8 (was 16x16x64): half the MFMA instructions at a 12%
// better measured rate (m55 4404 vs m16 3944 TOPS), deeper per-inst pipe ->
// fewer exposed dependency stalls (R6/R7 proved the kernel is chain-latency
// bound: 2x occupancy and -50% FETCH both moved time ~0). 32x32 C-layout also
// gives 128B store segments (was 64B). Weight prefetch double-buffered again
// (R0-proven; R6 proved 3 vs 4 waves/SIMD is neutral, so +16 regs is free).
// LDS act tile layout UNCHANGED (16B channel-chunks, XOR swizzle); only the
// chunk index moves: (ks2*2 + lane>>5) ^ (colL&7).
// Tripwire: WRITE_SIZE must stay ~52-57MB (spill shows as +100MB).
__global__ __launch_bounds__(256) void bconv_kernel(
        const uint4* __restrict__ wI8v,
        const float* __restrict__ invG, const float* __restrict__ b0G,
        const float* __restrict__ x, float* __restrict__ out) {
    __shared__ uint4 actT[4 * 68 * 8];   // 34816 B: [rho][colL][cblk ^ (colL&7)]
    __shared__ float sInv[P_], sB0[P_];

    int tid = threadIdx.x;
    // XCD-chunked swizzle (R7: FETCH 81->40MB): orig&7 == XCD; 112 blocks
    // (4 whole images) per XCD chunk. Bijective: 896 % 8 == 0.
    int bid = (blockIdx.x & 7) * 112 + (blockIdx.x >> 3);
    int img = bid / 28;
    int rp  = bid % 28;
    int r0  = rp * 2;

    int lane = tid & 63;
    int wi   = tid >> 6;
    int l31  = lane & 31;
    int kl   = lane >> 5;                // K-half selector for 32x32 fragments
    int m0   = wi * 32;

    if (tid < P_) { sInv[tid] = invG[tid]; sB0[tid] = b0G[tid]; }

    // ---- tap-0 weight prefetch: A-frag for 32x32x32: row=lane&31,
    // K-byte = kl*16 + b  ->  uint4 idx = p*72 + t*8 + ks2*2 + kl
    const uint4* wbase = wI8v + (size_t)(m0 + l31) * 72 + kl;
    i32x4 aw[2][4];                      // [buf][ks2]
    #pragma unroll
    for (int ks2 = 0; ks2 < 4; ++ks2)
        aw[0][ks2] = *(const i32x4*)&wbase[ks2 * 2];

    // ---- expand x signs -> i8 tile (+1/-1, 0 outside image), swizzled ------
    // (identical to verified R7 expansion)
    if (tid < 224) {
        int rho = tid / 56;
        int rr  = tid % 56;
        int cg  = rr / 14;               // channel group: c = cg*32 + ci
        int tq  = rr % 14;               // wv0 = tq*4
        int h   = r0 - 1 + rho;
        bool vh = ((unsigned)h < (unsigned)H_);
        uint32_t c0 = vh ? 0x01010101u : 0u;   // invalid row -> all-zero bytes
        uint32_t cf = vh ? 0xFEu       : 0u;
        const uint32_t* xb = (const uint32_t*)x
            + ((size_t)img * C_ + cg * 32) * HW_ + (vh ? h : 0) * W_ + tq * 4;
        int colL0 = tq * 4 + 1;                // cells colL 1..56 (wv 0..55)
        #pragma unroll
        for (int ph = 0; ph < 2; ++ph) {       // 16 channels per pass
            uint32_t cell0[4], cell1[4], cell2[4], cell3[4];
            #pragma unroll
            for (int d = 0; d < 4; ++d) {      // dword d = channels d*4..d*4+3
                uint32_t w0 = 0, w1 = 0, w2 = 0, w3 = 0;
                if (vh) {
                    #pragma unroll
                    for (int i = 0; i < 4; ++i) {
                        uint4 u = *(const uint4*)(xb + (size_t)(ph * 16 + d * 4 + i) * HW_);
                        uint32_t sh = i * 8;
                        w0 |= (u.x >> 31) << sh;
                        w1 |= (u.y >> 31) << sh;
                        w2 |= (u.z >> 31) << sh;
                        w3 |= (u.w >> 31) << sh;
                    }
                }
                cell0[d] = c0 + w0 * cf;
                cell1[d] = c0 + w1 * cf;
                cell2[d] = c0 + w2 * cf;
                cell3[d] = c0 + w3 * cf;
            }
            int cb = cg * 2 + ph;              // 16B chunk index (16 channels)
            actT[(rho * 68 + colL0 + 0) * 8 + (cb ^ ((colL0 + 0) & 7))] =
                make_uint4(cell0[0], cell0[1], cell0[2], cell0[3]);
            actT[(rho * 68 + colL0 + 1) * 8 + (cb ^ ((colL0 + 1) & 7))] =
                make_uint4(cell1[0], cell1[1], cell1[2], cell1[3]);
            actT[(rho * 68 + colL0 + 2) * 8 + (cb ^ ((colL0 + 2) & 7))] =
                make_uint4(cell2[0], cell2[1], cell2[2], cell2[3]);
            actT[(rho * 68 + colL0 + 3) * 8 + (cb ^ ((colL0 + 3) & 7))] =
                make_uint4(cell3[0], cell3[1], cell3[2], cell3[3]);
        }
    } else {
        // 32 threads zero the halo cells: colL==0 and colL 57..67, all 4 rows
        int z = tid - 224;
        #pragma unroll
        for (int rep = 0; rep < 2; ++rep) {
            int e = z + rep * 32;
            if (e < 48) {
                int rho  = e / 12;
                int jj   = e % 12;
                int colL = jj ? (56 + jj) : 0;
                int base = (rho * 68 + colL) * 8;
                #pragma unroll
                for (int s = 0; s < 8; ++s) actT[base + s] = make_uint4(0u,0u,0u,0u);
            }
        }
    }

    __syncthreads();                     // the ONLY barrier

    i32x16 acc[4];                       // [px-tile of 32]; init after barrier
    #pragma unroll
    for (int t = 0; t < 4; ++t)
        #pragma unroll
        for (int e = 0; e < 16; ++e) acc[t][e] = 0;

    #pragma unroll 1
    for (int t9 = 0; t9 < 9; ++t9) {
        int nb = t9 & 1;
        if (t9 < 8) {                    // prefetch next tap's weights (L2-hot)
            #pragma unroll
            for (int ks2 = 0; ks2 < 4; ++ks2)
                aw[nb ^ 1][ks2] = *(const i32x4*)&wbase[(t9 + 1) * 8 + ks2 * 2];
        }
        int dh = t9 / 3, dw = t9 % 3;
        #pragma unroll
        for (int ks2 = 0; ks2 < 4; ++ks2) {
            #pragma unroll
            for (int t = 0; t < 4; ++t) {
                int pxg  = t * 32 + l31;
                int colL = (pxg & 63) + dw;
                int rho  = (pxg >> 6) + dh;
                // B-frag: col=lane&31 (pixel), K-byte = kl*16+b -> chunk ks2*2+kl
                i32x4 bf = *(const i32x4*)&actT[(rho * 68 + colL) * 8
                                                + ((ks2 * 2 + kl) ^ (colL & 7))];
                acc[t] = __builtin_amdgcn_mfma_i32_32x32x32_i8(aw[nb][ks2], bf, acc[t], 0, 0, 0);
            }
        }
    }

    // ---- epilogue: BN + residual. 32x32 C-layout: col(px)=lane&31,
    // row(ch) = (reg&3) + 8*(reg>>2) + 4*kl. Stores coalesce in 128B runs.
    // aw is dead here; hoist the 16 per-lane channel scales into regs.
    float invR[16], b0R[16];
    #pragma unroll
    for (int reg = 0; reg < 16; ++reg) {
        int m = m0 + (reg & 3) + 8 * (reg >> 2) + 4 * kl;
        invR[reg] = sInv[m];
        b0R[reg]  = sB0[m];
    }
    #pragma unroll
    for (int t = 0; t < 4; ++t) {
        int pxg = t * 32 + l31;
        int w   = pxg & 63;
        if (w < W_) {
            int orow = r0 + (pxg >> 6);
            size_t pixOff = (size_t)img * P_ * HW_ + (size_t)orow * W_ + w;
            #pragma unroll
            for (int reg = 0; reg < 16; ++reg) {
                int m = m0 + (reg & 3) + 8 * (reg >> 2) + 4 * kl;
                size_t off = pixOff + (size_t)m * HW_;
                out[off] = (float)acc[t][reg] * invR[reg] + b0R[reg] + x[off];
            }
        }
    }
}

extern "C" void kernel_launch(void* const* d_in, const int* in_sizes, int n_in,
                              void* d_out, int out_size, void* d_ws, size_t ws_size,
                              hipStream_t stream) {
    const float* x      = (const float*)d_in[0];
    const float* weight = (const float*)d_in[1];
    const float* bias   = (const float*)d_in[2];
    const float* gamma  = (const float*)d_in[3];
    const float* beta   = (const float*)d_in[4];
    const float* mean   = (const float*)d_in[5];
    const float* var    = (const float*)d_in[6];
    float* out = (float*)d_out;

    uint8_t*  ws    = (uint8_t*)d_ws;
    uint32_t* wI8   = (uint32_t*)ws;
    float*    invG  = (float*)(ws + WI8_BYTES);
    float*    b0G   = invG + P_;

    wpack_kernel<<<144, 256, 0, stream>>>(weight, bias, gamma, beta, mean, var, wI8, invG, b0G);
    bconv_kernel<<<32 * 28, 256, 0, stream>>>((const uint4*)wI8, invG, b0G, x, out);
}

// Round 9
// 172.366 us; speedup vs baseline: 1.0214x; 1.0214x over previous
//
#include <hip/hip_runtime.h>
#include <stdint.h>

#define N_  32
#define C_  128
#define H_  56
#define W_  56
#define HW_ 3136
#define P_  128

using i32x4 = __attribute__((ext_vector_type(4))) int;

// ws layout (bytes):
//   wI8 : P*1152 = 147,456  (i8 +1/-1 weights, [p][tap*128+c])
//   inv : P*4
//   b0  : P*4
#define WI8_BYTES (P_*1152)

// ------- pack weights to i8 +1/-1 in [p][t*128+c] layout; fold BN ------------
__global__ __launch_bounds__(256) void wpack_kernel(const float* __restrict__ weight,
        const float* __restrict__ bias, const float* __restrict__ gamma,
        const float* __restrict__ beta, const float* __restrict__ mean,
        const float* __restrict__ var,
        uint32_t* __restrict__ wI8, float* __restrict__ invG, float* __restrict__ b0G) {
    int gid = blockIdx.x * 256 + threadIdx.x;        // 144 blocks = 36864 dwords
    int p   = gid / 288;
    int rem = gid % 288;
    int k   = rem * 4;                               // k = t*128 + c
    int tp  = k >> 7;
    int c   = k & 127;
    uint32_t d = 0;
    #pragma unroll
    for (int i2 = 0; i2 < 4; ++i2) {
        float v = weight[((size_t)p * C_ + c + i2) * 9 + tp];
        uint32_t by = (v >= 0.f) ? 0x01u : 0xFFu;
        d |= by << (8 * i2);
    }
    wI8[gid] = d;
    if (blockIdx.x == 0 && threadIdx.x < P_) {
        int pp = threadIdx.x;
        float inv = gamma[pp] * rsqrtf(var[pp] + 1e-5f);
        invG[pp] = inv;
        b0G[pp]  = bias[pp] * inv + beta[pp] - mean[pp] * inv;
    }
}

// ------- fused: sign-binarize x in-kernel + binary conv via i8 MFMA + BN + res
// Block: 2 output rows x 64 cols x 128 out-ch.
// R9: wave remap 32ch x 128px  ->  64ch x 64px (wave wi: ch-half wi&1,
// output row wi>>1). Each LDS B-fragment now feeds 4 MFMAs instead of 2:
// ds_read_b128 per wave 144 -> 72, halving the ~15-20us main-loop LDS floor
// (the largest single term in R7's 57us; R6/R7 proved occupancy and HBM
// locality are not binding). MFMA shape back to 16x16x64 (R8's 32x32 made
// colL's bank contribution vanish mod 32 -> 4-way conflicts, 788K->2.85M).
// Weights single-buffered 8 loads/tap (R6: sb==db at 3-4 waves/SIMD).
// Read pattern per bf is IDENTICAL to R7 (16 consecutive colL x 4 q-slots,
// free 2-way aliasing). Expansion / epilogue-coalescing / XCD swizzle kept.
// Tripwire: WRITE_SIZE ~52-57MB (spill shows as +100MB).
__global__ __launch_bounds__(256) void bconv_kernel(
        const uint4* __restrict__ wI8v,
        const float* __restrict__ invG, const float* __restrict__ b0G,
        const float* __restrict__ x, float* __restrict__ out) {
    __shared__ uint4 actT[4 * 68 * 8];   // 34816 B: [rho][colL][cblk ^ (colL&7)]
    __shared__ float sInv[P_], sB0[P_];

    int tid = threadIdx.x;
    // XCD-chunked swizzle (R7: FETCH 81->40MB): orig&7 == XCD; 112 blocks
    // (4 whole images) per XCD chunk. Bijective: 896 % 8 == 0.
    int bid = (blockIdx.x & 7) * 112 + (blockIdx.x >> 3);
    int img = bid / 28;
    int rp  = bid % 28;
    int r0  = rp * 2;

    int lane = tid & 63;
    int wi   = tid >> 6;
    int q    = lane >> 4;
    int l15  = lane & 15;
    int hi   = wi & 1;                   // channel half: m0 = hi*64
    int rr   = wi >> 1;                  // output row within the pair
    int m0   = hi * 64;

    if (tid < P_) { sInv[tid] = invG[tid]; sB0[tid] = b0G[tid]; }

    // ---- expand x signs -> i8 tile (+1/-1, 0 outside image), swizzled ------
    // (identical to verified R7 expansion)
    if (tid < 224) {
        int rho = tid / 56;
        int rr2 = tid % 56;
        int cg  = rr2 / 14;              // channel group: c = cg*32 + ci
        int tq  = rr2 % 14;              // wv0 = tq*4
        int h   = r0 - 1 + rho;
        bool vh = ((unsigned)h < (unsigned)H_);
        uint32_t c0 = vh ? 0x01010101u : 0u;   // invalid row -> all-zero bytes
        uint32_t cf = vh ? 0xFEu       : 0u;
        const uint32_t* xb = (const uint32_t*)x
            + ((size_t)img * C_ + cg * 32) * HW_ + (vh ? h : 0) * W_ + tq * 4;
        int colL0 = tq * 4 + 1;                // cells colL 1..56 (wv 0..55)
        #pragma unroll
        for (int ph = 0; ph < 2; ++ph) {       // 16 channels per pass
            uint32_t cell0[4], cell1[4], cell2[4], cell3[4];
            #pragma unroll
            for (int d = 0; d < 4; ++d) {      // dword d = channels d*4..d*4+3
                uint32_t w0 = 0, w1 = 0, w2 = 0, w3 = 0;
                if (vh) {
                    #pragma unroll
                    for (int i = 0; i < 4; ++i) {
                        uint4 u = *(const uint4*)(xb + (size_t)(ph * 16 + d * 4 + i) * HW_);
                        uint32_t sh = i * 8;
                        w0 |= (u.x >> 31) << sh;
                        w1 |= (u.y >> 31) << sh;
                        w2 |= (u.z >> 31) << sh;
                        w3 |= (u.w >> 31) << sh;
                    }
                }
                cell0[d] = c0 + w0 * cf;
                cell1[d] = c0 + w1 * cf;
                cell2[d] = c0 + w2 * cf;
                cell3[d] = c0 + w3 * cf;
            }
            int cb = cg * 2 + ph;              // 16B chunk index (16 channels)
            actT[(rho * 68 + colL0 + 0) * 8 + (cb ^ ((colL0 + 0) & 7))] =
                make_uint4(cell0[0], cell0[1], cell0[2], cell0[3]);
            actT[(rho * 68 + colL0 + 1) * 8 + (cb ^ ((colL0 + 1) & 7))] =
                make_uint4(cell1[0], cell1[1], cell1[2], cell1[3]);
            actT[(rho * 68 + colL0 + 2) * 8 + (cb ^ ((colL0 + 2) & 7))] =
                make_uint4(cell2[0], cell2[1], cell2[2], cell2[3]);
            actT[(rho * 68 + colL0 + 3) * 8 + (cb ^ ((colL0 + 3) & 7))] =
                make_uint4(cell3[0], cell3[1], cell3[2], cell3[3]);
        }
    } else {
        // 32 threads zero the halo cells: colL==0 and colL 57..67, all 4 rows
        int z = tid - 224;
        #pragma unroll
        for (int rep = 0; rep < 2; ++rep) {
            int e = z + rep * 32;
            if (e < 48) {
                int rho  = e / 12;
                int jj   = e % 12;
                int colL = jj ? (56 + jj) : 0;
                int base = (rho * 68 + colL) * 8;
                #pragma unroll
                for (int s = 0; s < 8; ++s) actT[base + s] = make_uint4(0u,0u,0u,0u);
            }
        }
    }

    __syncthreads();                     // the ONLY barrier

    i32x4 acc[4][4];                     // [m-tile][j]; init after barrier
    #pragma unroll
    for (int m = 0; m < 4; ++m)
        #pragma unroll
        for (int j = 0; j < 4; ++j)
            #pragma unroll
            for (int e = 0; e < 4; ++e) acc[m][j][e] = 0;

    #pragma unroll 1
    for (int t9 = 0; t9 < 9; ++t9) {
        // single-buffered per-tap weights: 8 x dwordx4, L2-hot
        i32x4 aw[4][2];                  // [m-tile][ks]
        #pragma unroll
        for (int m = 0; m < 4; ++m)
            #pragma unroll
            for (int ks = 0; ks < 2; ++ks)
                aw[m][ks] = *(const i32x4*)&wI8v[(size_t)(m0 + m*16 + l15) * 72
                                                 + t9 * 8 + ks * 4 + q];
        int dh = t9 / 3, dw = t9 % 3;
        int rho = rr + dh;
        #pragma unroll
        for (int ks = 0; ks < 2; ++ks) {
            #pragma unroll
            for (int j = 0; j < 4; ++j) {
                int colL = j * 16 + l15 + dw;
                i32x4 bf = *(const i32x4*)&actT[(rho * 68 + colL) * 8
                                                + ((ks * 4 + q) ^ (colL & 7))];
                #pragma unroll
                for (int m = 0; m < 4; ++m)
                    acc[m][j] = __builtin_amdgcn_mfma_i32_16x16x64_i8(aw[m][ks], bf, acc[m][j], 0, 0, 0);
            }
        }
    }

    // ---- epilogue: BN + residual, coalesced 64B segments; scale/shift read
    // straight from LDS ----
    #pragma unroll
    for (int j = 0; j < 4; ++j) {
        int w = j * 16 + l15;
        if (w < W_) {
            int orow = r0 + rr;
            size_t pixOff = (size_t)img * P_ * HW_ + (size_t)orow * W_ + w;
            #pragma unroll
            for (int m = 0; m < 4; ++m)
                #pragma unroll
                for (int reg = 0; reg < 4; ++reg) {
                    int ch = m0 + m * 16 + q * 4 + reg;
                    size_t off = pixOff + (size_t)ch * HW_;
                    out[off] = (float)acc[m][j][reg] * sInv[ch] + sB0[ch] + x[off];
                }
        }
    }
}

extern "C" void kernel_launch(void* const* d_in, const int* in_sizes, int n_in,
                              void* d_out, int out_size, void* d_ws, size_t ws_size,
                              hipStream_t stream) {
    const float* x      = (const float*)d_in[0];
    const float* weight = (const float*)d_in[1];
    const float* bias   = (const float*)d_in[2];
    const float* gamma  = (const float*)d_in[3];
    const float* beta   = (const float*)d_in[4];
    const float* mean   = (const float*)d_in[5];
    const float* var    = (const float*)d_in[6];
    float* out = (float*)d_out;

    uint8_t*  ws    = (uint8_t*)d_ws;
    uint32_t* wI8   = (uint32_t*)ws;
    float*    invG  = (float*)(ws + WI8_BYTES);
    float*    b0G   = invG + P_;

    wpack_kernel<<<144, 256, 0, stream>>>(weight, bias, gamma, beta, mean, var, wI8, invG, b0G);
    bconv_kernel<<<32 * 28, 256, 0, stream>>>((const uint4*)wI8, invG, b0G, x, out);
}

// Round 10
// 149.786 us; speedup vs baseline: 1.1754x; 1.1508x over previous
//
#include <hip/hip_runtime.h>
#include <stdint.h>

#define N_  32
#define C_  128
#define H_  56
#define W_  56
#define HW_ 3136
#define P_  128

using i32x4 = __attribute__((ext_vector_type(4))) int;

// ws layout (bytes):
//   wI8 : P*1152 = 147,456  (i8 +1/-1 weights, [p][tap*128+c])
//   inv : P*4
//   b0  : P*4
#define WI8_BYTES (P_*1152)

// ------- pack weights to i8 +1/-1 in [p][t*128+c] layout; fold BN ------------
__global__ __launch_bounds__(256) void wpack_kernel(const float* __restrict__ weight,
        const float* __restrict__ bias, const float* __restrict__ gamma,
        const float* __restrict__ beta, const float* __restrict__ mean,
        const float* __restrict__ var,
        uint32_t* __restrict__ wI8, float* __restrict__ invG, float* __restrict__ b0G) {
    int gid = blockIdx.x * 256 + threadIdx.x;        // 144 blocks = 36864 dwords
    int p   = gid / 288;
    int rem = gid % 288;
    int k   = rem * 4;                               // k = t*128 + c
    int tp  = k >> 7;
    int c   = k & 127;
    uint32_t d = 0;
    #pragma unroll
    for (int i2 = 0; i2 < 4; ++i2) {
        float v = weight[((size_t)p * C_ + c + i2) * 9 + tp];
        uint32_t by = (v >= 0.f) ? 0x01u : 0xFFu;
        d |= by << (8 * i2);
    }
    wI8[gid] = d;
    if (blockIdx.x == 0 && threadIdx.x < P_) {
        int pp = threadIdx.x;
        float inv = gamma[pp] * rsqrtf(var[pp] + 1e-5f);
        invG[pp] = inv;
        b0G[pp]  = bias[pp] * inv + beta[pp] - mean[pp] * inv;
    }
}

// ------- fused: sign-binarize x in-kernel + binary conv via i8 MFMA + BN + res
// Block: 2 output rows x 64 cols x 128 out-ch (R7 base: 56.7us verified;
// R8 32x32-MFMA and R9 wave-remap both regressed -> reverted).
// R10 change: EPILOGUE ONLY. The R7 epilogue issued 128 scalar 4B VMEM ops
// (64B segments) + 128 divergent ds_read_b32 (sInv/sB0) per thread -- as many
// instructions as the whole main loop. Now: after a barrier, each wave
// scatters its BN-applied fragment into a private 16x132-float LDS region
// (reusing actT), then reads back transposed so stores/residual-loads are
// float4 in 4x224B fully-contiguous runs: VMEM 128 -> 32 inst/thread at 3.5x
// payload; BN scales hoisted (16 LDS reads, was 128).
// Expansion / main loop / XCD swizzle identical to R7.
// Tripwire: WRITE_SIZE ~52-57MB (spill shows as +100MB).
__global__ __launch_bounds__(256) void bconv_kernel(
        const uint4* __restrict__ wI8v,
        const float* __restrict__ invG, const float* __restrict__ b0G,
        const float* __restrict__ x, float* __restrict__ out) {
    __shared__ uint4 actT[4 * 68 * 8];   // 34816 B: [rho][colL][cblk ^ (colL&7)]
    __shared__ float sInv[P_], sB0[P_];

    int tid = threadIdx.x;
    // XCD-chunked swizzle (R7: FETCH 81->40MB): orig&7 == XCD; 112 blocks
    // (4 whole images) per XCD chunk. Bijective: 896 % 8 == 0.
    int bid = (blockIdx.x & 7) * 112 + (blockIdx.x >> 3);
    int img = bid / 28;
    int rp  = bid % 28;
    int r0  = rp * 2;

    int lane = tid & 63;
    int wi   = tid >> 6;
    int q    = lane >> 4;
    int l15  = lane & 15;
    int m0   = wi * 32;

    if (tid < P_) { sInv[tid] = invG[tid]; sB0[tid] = b0G[tid]; }

    // ---- tap-0 weight prefetch (double-buffered across taps, R7-proven) ----
    const uint4* wbase = wI8v + (size_t)(m0 + l15) * 72;   // +mi*16*72 below
    i32x4 aw[2][2][2];                   // [buf][mi][ks]
    #pragma unroll
    for (int mi = 0; mi < 2; ++mi)
        #pragma unroll
        for (int ks = 0; ks < 2; ++ks)
            aw[0][mi][ks] = *(const i32x4*)&wI8v[(size_t)(m0 + mi*16 + l15) * 72
                                                 + ks * 4 + q];

    // ---- expand x signs -> i8 tile (+1/-1, 0 outside image), swizzled ------
    // (identical to verified R7 expansion)
    if (tid < 224) {
        int rho = tid / 56;
        int rr2 = tid % 56;
        int cg  = rr2 / 14;              // channel group: c = cg*32 + ci
        int tq  = rr2 % 14;              // wv0 = tq*4
        int h   = r0 - 1 + rho;
        bool vh = ((unsigned)h < (unsigned)H_);
        uint32_t c0 = vh ? 0x01010101u : 0u;   // invalid row -> all-zero bytes
        uint32_t cf = vh ? 0xFEu       : 0u;
        const uint32_t* xb = (const uint32_t*)x
            + ((size_t)img * C_ + cg * 32) * HW_ + (vh ? h : 0) * W_ + tq * 4;
        int colL0 = tq * 4 + 1;                // cells colL 1..56 (wv 0..55)
        #pragma unroll
        for (int ph = 0; ph < 2; ++ph) {       // 16 channels per pass
            uint32_t cell0[4], cell1[4], cell2[4], cell3[4];
            #pragma unroll
            for (int d = 0; d < 4; ++d) {      // dword d = channels d*4..d*4+3
                uint32_t w0 = 0, w1 = 0, w2 = 0, w3 = 0;
                if (vh) {
                    #pragma unroll
                    for (int i = 0; i < 4; ++i) {
                        uint4 u = *(const uint4*)(xb + (size_t)(ph * 16 + d * 4 + i) * HW_);
                        uint32_t sh = i * 8;
                        w0 |= (u.x >> 31) << sh;
                        w1 |= (u.y >> 31) << sh;
                        w2 |= (u.z >> 31) << sh;
                        w3 |= (u.w >> 31) << sh;
                    }
                }
                cell0[d] = c0 + w0 * cf;
                cell1[d] = c0 + w1 * cf;
                cell2[d] = c0 + w2 * cf;
                cell3[d] = c0 + w3 * cf;
            }
            int cb = cg * 2 + ph;              // 16B chunk index (16 channels)
            actT[(rho * 68 + colL0 + 0) * 8 + (cb ^ ((colL0 + 0) & 7))] =
                make_uint4(cell0[0], cell0[1], cell0[2], cell0[3]);
            actT[(rho * 68 + colL0 + 1) * 8 + (cb ^ ((colL0 + 1) & 7))] =
                make_uint4(cell1[0], cell1[1], cell1[2], cell1[3]);
            actT[(rho * 68 + colL0 + 2) * 8 + (cb ^ ((colL0 + 2) & 7))] =
                make_uint4(cell2[0], cell2[1], cell2[2], cell2[3]);
            actT[(rho * 68 + colL0 + 3) * 8 + (cb ^ ((colL0 + 3) & 7))] =
                make_uint4(cell3[0], cell3[1], cell3[2], cell3[3]);
        }
    } else {
        // 32 threads zero the halo cells: colL==0 and colL 57..67, all 4 rows
        int z = tid - 224;
        #pragma unroll
        for (int rep = 0; rep < 2; ++rep) {
            int e = z + rep * 32;
            if (e < 48) {
                int rho  = e / 12;
                int jj   = e % 12;
                int colL = jj ? (56 + jj) : 0;
                int base = (rho * 68 + colL) * 8;
                #pragma unroll
                for (int s = 0; s < 8; ++s) actT[base + s] = make_uint4(0u,0u,0u,0u);
            }
        }
    }

    __syncthreads();                     // barrier 1: act tile ready

    i32x4 acc[2][8];                     // init after barrier
    #pragma unroll
    for (int mi = 0; mi < 2; ++mi)
        #pragma unroll
        for (int j = 0; j < 8; ++j)
            #pragma unroll
            for (int e = 0; e < 4; ++e) acc[mi][j][e] = 0;

    #pragma unroll 1
    for (int t9 = 0; t9 < 9; ++t9) {
        int nb = t9 & 1;
        if (t9 < 8) {                    // prefetch next tap's weights (L2-hot)
            #pragma unroll
            for (int mi = 0; mi < 2; ++mi)
                #pragma unroll
                for (int ks = 0; ks < 2; ++ks)
                    aw[nb ^ 1][mi][ks] = *(const i32x4*)&wI8v[(size_t)(m0 + mi*16 + l15) * 72
                                                              + (t9 + 1) * 8 + ks * 4 + q];
        }
        int dh = t9 / 3, dw = t9 % 3;
        #pragma unroll
        for (int ks = 0; ks < 2; ++ks) {
            #pragma unroll
            for (int j = 0; j < 8; ++j) {
                int n    = j * 16 + l15;
                int colL = (n & 63) + dw;
                int rho  = (n >> 6) + dh;
                i32x4 bf = *(const i32x4*)&actT[(rho * 68 + colL) * 8 + ((ks * 4 + q) ^ (colL & 7))];
                acc[0][j] = __builtin_amdgcn_mfma_i32_16x16x64_i8(aw[nb][0][ks], bf, acc[0][j], 0, 0, 0);
                acc[1][j] = __builtin_amdgcn_mfma_i32_16x16x64_i8(aw[nb][1][ks], bf, acc[1][j], 0, 0, 0);
            }
        }
    }

    __syncthreads();                     // barrier 2: actT reads done, reuse as S

    // ---- epilogue: transpose through LDS -> fully-coalesced float4 I/O ----
    // Per-wave private region: 16 ch x 132 floats (8448B); 4 waves = 33792B,
    // fits inside actT. Write side: S[ch_local][n] (b32, 2-way-free banks).
    // Read side: 56 lanes = (ch4 = lane/14) x (wq = lane%14); each float4
    // store/load covers 4 contiguous 224B runs.
    float* S = (float*)actT + wi * (16 * 132);
    #pragma unroll
    for (int mi = 0; mi < 2; ++mi) {
        float invR[4], b0R[4];
        #pragma unroll
        for (int reg = 0; reg < 4; ++reg) {
            int m = m0 + mi * 16 + q * 4 + reg;
            invR[reg] = sInv[m];
            b0R[reg]  = sB0[m];
        }
        #pragma unroll
        for (int j = 0; j < 8; ++j) {
            int n = j * 16 + l15;
            #pragma unroll
            for (int reg = 0; reg < 4; ++reg)
                S[(q * 4 + reg) * 132 + n] = (float)acc[mi][j][reg] * invR[reg] + b0R[reg];
        }
        asm volatile("s_waitcnt lgkmcnt(0)" ::: "memory");   // wave-local RAW
        if (lane < 56) {
            int ch4 = lane / 14;
            int wq  = lane % 14;
            #pragma unroll
            for (int k = 0; k < 4; ++k) {
                int chl = k * 4 + ch4;            // 0..15
                int ch  = m0 + mi * 16 + chl;
                #pragma unroll
                for (int rr2 = 0; rr2 < 2; ++rr2) {
                    float4 v = *(float4*)&S[chl * 132 + rr2 * 64 + wq * 4];
                    size_t off = (size_t)img * P_ * HW_ + (size_t)ch * HW_
                               + (size_t)(r0 + rr2) * W_ + wq * 4;
                    const float4 xr = *(const float4*)&x[off];
                    v.x += xr.x; v.y += xr.y; v.z += xr.z; v.w += xr.w;
                    *(float4*)&out[off] = v;
                }
            }
        }
        if (mi == 0)
            asm volatile("s_waitcnt lgkmcnt(0)" ::: "memory"); // WAR before reuse
    }
}

extern "C" void kernel_launch(void* const* d_in, const int* in_sizes, int n_in,
                              void* d_out, int out_size, void* d_ws, size_t ws_size,
                              hipStream_t stream) {
    const float* x      = (const float*)d_in[0];
    const float* weight = (const float*)d_in[1];
    const float* bias   = (const float*)d_in[2];
    const float* gamma  = (const float*)d_in[3];
    const float* beta   = (const float*)d_in[4];
    const float* mean   = (const float*)d_in[5];
    const float* var    = (const float*)d_in[6];
    float* out = (float*)d_out;

    uint8_t*  ws    = (uint8_t*)d_ws;
    uint32_t* wI8   = (uint32_t*)ws;
    float*    invG  = (float*)(ws + WI8_BYTES);
    float*    b0G   = invG + P_;

    wpack_kernel<<<144, 256, 0, stream>>>(weight, bias, gamma, beta, mean, var, wI8, invG, b0G);
    bconv_kernel<<<32 * 28, 256, 0, stream>>>((const uint4*)wI8, invG, b0G, x, out);
}

// Round 12
// 147.400 us; speedup vs baseline: 1.1944x; 1.0162x over previous
//
#include <hip/hip_runtime.h>
#include <stdint.h>

#define N_  32
#define C_  128
#define H_  56
#define W_  56
#define HW_ 3136
#define P_  128

using i32x4 = __attribute__((ext_vector_type(4))) int;

// ws layout (bytes), big-workspace path:
//   act : 32*58*8704 = 16,154,624  (pre-swizzled NHWC i8 rows, WITH halo rows:
//         row 0 and row 57 of each image are zeros; row r = image row r-1)
//   wI8 : P*1152     = 147,456
//   inv : P*4 ; b0 : P*4
#define ACT_ROWB   8704
#define ACT_NROWS  58
#define ACT_BYTES  ((size_t)N_ * ACT_NROWS * ACT_ROWB)
#define WI8_BYTES  (P_*1152)

// ------- pack weights to i8 +1/-1 in [p][t*128+c] layout; fold BN ------------
__global__ __launch_bounds__(256) void wpack_kernel(const float* __restrict__ weight,
        const float* __restrict__ bias, const float* __restrict__ gamma,
        const float* __restrict__ beta, const float* __restrict__ mean,
        const float* __restrict__ var,
        uint32_t* __restrict__ wI8, float* __restrict__ invG, float* __restrict__ b0G) {
    int gid = blockIdx.x * 256 + threadIdx.x;        // 144 blocks = 36864 dwords
    int p   = gid / 288;
    int rem = gid % 288;
    int k   = rem * 4;                               // k = t*128 + c
    int tp  = k >> 7;
    int c   = k & 127;
    uint32_t d = 0;
    #pragma unroll
    for (int i2 = 0; i2 < 4; ++i2) {
        float v = weight[((size_t)p * C_ + c + i2) * 9 + tp];
        uint32_t by = (v >= 0.f) ? 0x01u : 0xFFu;
        d |= by << (8 * i2);
    }
    wI8[gid] = d;
    if (blockIdx.x == 0 && threadIdx.x < P_) {
        int pp = threadIdx.x;
        float inv = gamma[pp] * rsqrtf(var[pp] + 1e-5f);
        invG[pp] = inv;
        b0G[pp]  = bias[pp] * inv + beta[pp] - mean[pp] * inv;
    }
}

// ------- pack_act: x (NCHW f32) -> pre-swizzled NHWC i8 rows + halo ---------
// One block per (n, rowIdx 0..57). rowIdx 0 / 57 are zero halo rows; rowIdx r
// packs image row h=r-1. Row layout: 68 cols x 8 chunks of 16B; col 0 and
// 57..67 zero (halo cols built in); chunk cb stored at slot cb^(colL&7)
// (bconv's LDS XOR swizzle), so bconv copies rows LINEARLY via DMA.
__global__ __launch_bounds__(256) void pack_act(const float* __restrict__ x,
                                                uint8_t* __restrict__ act) {
    __shared__ uint32_t S[56 * 33];      // [w][c4] dwords, +1 pad per row
    int bid = blockIdx.x;                // 0..N_*58-1
    int n   = bid / ACT_NROWS, ridx = bid % ACT_NROWS;
    int tid = threadIdx.x;
    uint8_t* rowG = act + (size_t)bid * ACT_ROWB;
    if (ridx == 0 || ridx == ACT_NROWS - 1) {        // zero halo row
        #pragma unroll
        for (int j = 0; j < 3; ++j) {
            int k = j * 256 + tid;
            if (k < 544) *(uint4*)(rowG + (size_t)k * 16) = make_uint4(0u,0u,0u,0u);
        }
        return;
    }
    int h = ridx - 1;
    const uint32_t* xb = (const uint32_t*)x + (size_t)n * C_ * HW_ + h * W_;
    #pragma unroll
    for (int j = 0; j < 7; ++j) {        // 7*256 = 1792 = 32 c4-groups x 56 w
        int u  = j * 256 + tid;
        int c4 = u / 56;
        int w  = u - c4 * 56;
        const uint32_t* p = xb + (size_t)(c4 * 4) * HW_ + w;
        uint32_t s = (p[0] >> 31) | ((p[HW_] >> 31) << 8)
                   | ((p[2 * HW_] >> 31) << 16) | ((p[3 * HW_] >> 31) << 24);
        S[w * 33 + c4] = 0x01010101u + s * 0xFEu;
    }
    __syncthreads();
    #pragma unroll
    for (int j = 0; j < 3; ++j) {
        int k = j * 256 + tid;
        if (k < 544) {
            int colL = k >> 3, cb = k & 7;
            uint4 v = make_uint4(0u, 0u, 0u, 0u);
            if (colL >= 1 && colL <= 56) {
                int w = colL - 1;
                v.x = S[w * 33 + cb * 4 + 0];
                v.y = S[w * 33 + cb * 4 + 1];
                v.z = S[w * 33 + cb * 4 + 2];
                v.w = S[w * 33 + cb * 4 + 3];
            }
            int slot = cb ^ (colL & 7);  // pre-swizzled position
            *(uint4*)(rowG + (size_t)(colL * 8 + slot) * 16) = v;
        }
    }
}

// ------- bconv_dma: stage act tile via global_load_lds; conv + BN + residual -
// Main loop / epilogue / XCD swizzle byte-identical to the verified R7 kernel.
// R12 fix vs R11's FAIL: global_load_lds's LDS dest is wave-uniform base +
// lane*16 (m104) -- R11 had a DIVERGENT valid-row branch inside the staging
// loop, so edge blocks issued DMA with partial exec and a first-active-lane
// base -> corrupted tiles (absmax 1558). Now the halo rows live in the packed
// buffer (58 rows/image, rows 0 & 57 zero), staging is branch-free, and the
// only guard (cid < 2176 = 34 full waves) is wave-uniform.
__global__ __launch_bounds__(256) void bconv_dma(
        const uint4* __restrict__ wI8v,
        const float* __restrict__ invG, const float* __restrict__ b0G,
        const uint8_t* __restrict__ act,
        const float* __restrict__ x, float* __restrict__ out) {
    __shared__ uint4 actT[4 * 68 * 8];   // 34816 B: [rho][colL][slot]
    __shared__ float sInv[P_], sB0[P_];

    int tid = threadIdx.x;
    // XCD-chunked swizzle (R7: FETCH 81->40MB). Bijective: 896 % 8 == 0.
    int bid = (blockIdx.x & 7) * 112 + (blockIdx.x >> 3);
    int img = bid / 28;
    int rp  = bid % 28;
    int r0  = rp * 2;

    int lane = tid & 63;
    int wi   = tid >> 6;
    int q    = lane >> 4;
    int l15  = lane & 15;
    int m0   = wi * 32;

    if (tid < P_) { sInv[tid] = invG[tid]; sB0[tid] = b0G[tid]; }

    // ---- tap-0 weight prefetch (double-buffered across taps, R7-proven) ----
    i32x4 aw[2][2][2];                   // [buf][mi][ks]
    #pragma unroll
    for (int mi = 0; mi < 2; ++mi)
        #pragma unroll
        for (int ks = 0; ks < 2; ++ks)
            aw[0][mi][ks] = *(const i32x4*)&wI8v[(size_t)(m0 + mi*16 + l15) * 72
                                                 + ks * 4 + q];

    // ---- stage 4 act rows (2176 x 16B chunks) via branch-free DMA ----------
    // global row index for tile row rho is r0+rho (halo rows pre-zeroed).
    // cid contiguous per wave -> LDS dest = uniform base + lane*16. Guard
    // cid<2176 is wave-uniform (2176 = 34 waves exactly).
    const uint8_t* actG = act + (size_t)img * ACT_NROWS * ACT_ROWB;
    #pragma unroll
    for (int i = 0; i < 9; ++i) {
        int cid = i * 256 + tid;
        if (cid < 2176) {
            int rho    = cid / 544;
            int within = cid - rho * 544;
            __builtin_amdgcn_global_load_lds(
                (const uint32_t*)(actG + (size_t)(r0 + rho) * ACT_ROWB
                                       + (size_t)within * 16),
                (uint32_t*)&actT[cid], 16, 0, 0);
        }
    }

    __syncthreads();                     // drains vmcnt; act tile ready

    i32x4 acc[2][8];
    #pragma unroll
    for (int mi = 0; mi < 2; ++mi)
        #pragma unroll
        for (int j = 0; j < 8; ++j)
            #pragma unroll
            for (int e = 0; e < 4; ++e) acc[mi][j][e] = 0;

    for (int t9 = 0; t9 < 9; ++t9) {
        int nb = t9 & 1;
        if (t9 < 8) {                    // prefetch next tap's weights (L2-hot)
            #pragma unroll
            for (int mi = 0; mi < 2; ++mi)
                #pragma unroll
                for (int ks = 0; ks < 2; ++ks)
                    aw[nb ^ 1][mi][ks] = *(const i32x4*)&wI8v[(size_t)(m0 + mi*16 + l15) * 72
                                                              + (t9 + 1) * 8 + ks * 4 + q];
        }
        int dh = t9 / 3, dw = t9 % 3;
        #pragma unroll
        for (int ks = 0; ks < 2; ++ks) {
            #pragma unroll
            for (int j = 0; j < 8; ++j) {
                int n    = j * 16 + l15;
                int colL = (n & 63) + dw;
                int rho  = (n >> 6) + dh;
                i32x4 bf = *(const i32x4*)&actT[(rho * 68 + colL) * 8 + ((ks * 4 + q) ^ (colL & 7))];
                acc[0][j] = __builtin_amdgcn_mfma_i32_16x16x64_i8(aw[nb][0][ks], bf, acc[0][j], 0, 0, 0);
                acc[1][j] = __builtin_amdgcn_mfma_i32_16x16x64_i8(aw[nb][1][ks], bf, acc[1][j], 0, 0, 0);
            }
        }
    }

    // ---- epilogue: BN + residual, coalesced 64B segments (R7 exact) --------
    #pragma unroll
    for (int j = 0; j < 8; ++j) {
        int n = j * 16 + l15;
        int w = n & 63;
        if (w < W_) {
            int orow = r0 + (n >> 6);
            size_t pixOff = (size_t)img * P_ * HW_ + (size_t)orow * W_ + w;
            #pragma unroll
            for (int mi = 0; mi < 2; ++mi)
                #pragma unroll
                for (int reg = 0; reg < 4; ++reg) {
                    int m = m0 + mi * 16 + q * 4 + reg;
                    size_t off = pixOff + (size_t)m * HW_;
                    out[off] = (float)acc[mi][j][reg] * sInv[m] + sB0[m] + x[off];
                }
        }
    }
}

// ------- fallback: R7 fused kernel (verified 56.7us) -- used if ws too small -
__global__ __launch_bounds__(256) void bconv_fused(
        const uint4* __restrict__ wI8v,
        const float* __restrict__ invG, const float* __restrict__ b0G,
        const float* __restrict__ x, float* __restrict__ out) {
    __shared__ uint4 actT[4 * 68 * 8];
    __shared__ float sInv[P_], sB0[P_];

    int tid = threadIdx.x;
    int bid = (blockIdx.x & 7) * 112 + (blockIdx.x >> 3);
    int img = bid / 28;
    int rp  = bid % 28;
    int r0  = rp * 2;

    int lane = tid & 63;
    int wi   = tid >> 6;
    int q    = lane >> 4;
    int l15  = lane & 15;
    int m0   = wi * 32;

    if (tid < P_) { sInv[tid] = invG[tid]; sB0[tid] = b0G[tid]; }

    i32x4 aw[2][2][2];
    #pragma unroll
    for (int mi = 0; mi < 2; ++mi)
        #pragma unroll
        for (int ks = 0; ks < 2; ++ks)
            aw[0][mi][ks] = *(const i32x4*)&wI8v[(size_t)(m0 + mi*16 + l15) * 72
                                                 + ks * 4 + q];

    if (tid < 224) {
        int rho = tid / 56;
        int rr2 = tid % 56;
        int cg  = rr2 / 14;
        int tq  = rr2 % 14;
        int h   = r0 - 1 + rho;
        bool vh = ((unsigned)h < (unsigned)H_);
        uint32_t c0 = vh ? 0x01010101u : 0u;
        uint32_t cf = vh ? 0xFEu       : 0u;
        const uint32_t* xb = (const uint32_t*)x
            + ((size_t)img * C_ + cg * 32) * HW_ + (vh ? h : 0) * W_ + tq * 4;
        int colL0 = tq * 4 + 1;
        #pragma unroll
        for (int ph = 0; ph < 2; ++ph) {
            uint32_t cell0[4], cell1[4], cell2[4], cell3[4];
            #pragma unroll
            for (int d = 0; d < 4; ++d) {
                uint32_t w0 = 0, w1 = 0, w2 = 0, w3 = 0;
                if (vh) {
                    #pragma unroll
                    for (int i = 0; i < 4; ++i) {
                        uint4 u = *(const uint4*)(xb + (size_t)(ph * 16 + d * 4 + i) * HW_);
                        uint32_t sh = i * 8;
                        w0 |= (u.x >> 31) << sh;
                        w1 |= (u.y >> 31) << sh;
                        w2 |= (u.z >> 31) << sh;
                        w3 |= (u.w >> 31) << sh;
                    }
                }
                cell0[d] = c0 + w0 * cf;
                cell1[d] = c0 + w1 * cf;
                cell2[d] = c0 + w2 * cf;
                cell3[d] = c0 + w3 * cf;
            }
            int cb = cg * 2 + ph;
            actT[(rho * 68 + colL0 + 0) * 8 + (cb ^ ((colL0 + 0) & 7))] =
                make_uint4(cell0[0], cell0[1], cell0[2], cell0[3]);
            actT[(rho * 68 + colL0 + 1) * 8 + (cb ^ ((colL0 + 1) & 7))] =
                make_uint4(cell1[0], cell1[1], cell1[2], cell1[3]);
            actT[(rho * 68 + colL0 + 2) * 8 + (cb ^ ((colL0 + 2) & 7))] =
                make_uint4(cell2[0], cell2[1], cell2[2], cell2[3]);
            actT[(rho * 68 + colL0 + 3) * 8 + (cb ^ ((colL0 + 3) & 7))] =
                make_uint4(cell3[0], cell3[1], cell3[2], cell3[3]);
        }
    } else {
        int z = tid - 224;
        #pragma unroll
        for (int rep = 0; rep < 2; ++rep) {
            int e = z + rep * 32;
            if (e < 48) {
                int rho  = e / 12;
                int jj   = e % 12;
                int colL = jj ? (56 + jj) : 0;
                int base = (rho * 68 + colL) * 8;
                #pragma unroll
                for (int s = 0; s < 8; ++s) actT[base + s] = make_uint4(0u,0u,0u,0u);
            }
        }
    }

    __syncthreads();

    i32x4 acc[2][8];
    #pragma unroll
    for (int mi = 0; mi < 2; ++mi)
        #pragma unroll
        for (int j = 0; j < 8; ++j)
            #pragma unroll
            for (int e = 0; e < 4; ++e) acc[mi][j][e] = 0;

    for (int t9 = 0; t9 < 9; ++t9) {
        int nb = t9 & 1;
        if (t9 < 8) {
            #pragma unroll
            for (int mi = 0; mi < 2; ++mi)
                #pragma unroll
                for (int ks = 0; ks < 2; ++ks)
                    aw[nb ^ 1][mi][ks] = *(const i32x4*)&wI8v[(size_t)(m0 + mi*16 + l15) * 72
                                                              + (t9 + 1) * 8 + ks * 4 + q];
        }
        int dh = t9 / 3, dw = t9 % 3;
        #pragma unroll
        for (int ks = 0; ks < 2; ++ks) {
            #pragma unroll
            for (int j = 0; j < 8; ++j) {
                int n    = j * 16 + l15;
                int colL = (n & 63) + dw;
                int rho  = (n >> 6) + dh;
                i32x4 bf = *(const i32x4*)&actT[(rho * 68 + colL) * 8 + ((ks * 4 + q) ^ (colL & 7))];
                acc[0][j] = __builtin_amdgcn_mfma_i32_16x16x64_i8(aw[nb][0][ks], bf, acc[0][j], 0, 0, 0);
                acc[1][j] = __builtin_amdgcn_mfma_i32_16x16x64_i8(aw[nb][1][ks], bf, acc[1][j], 0, 0, 0);
            }
        }
    }

    #pragma unroll
    for (int j = 0; j < 8; ++j) {
        int n = j * 16 + l15;
        int w = n & 63;
        if (w < W_) {
            int orow = r0 + (n >> 6);
            size_t pixOff = (size_t)img * P_ * HW_ + (size_t)orow * W_ + w;
            #pragma unroll
            for (int mi = 0; mi < 2; ++mi)
                #pragma unroll
                for (int reg = 0; reg < 4; ++reg) {
                    int m = m0 + mi * 16 + q * 4 + reg;
                    size_t off = pixOff + (size_t)m * HW_;
                    out[off] = (float)acc[mi][j][reg] * sInv[m] + sB0[m] + x[off];
                }
        }
    }
}

extern "C" void kernel_launch(void* const* d_in, const int* in_sizes, int n_in,
                              void* d_out, int out_size, void* d_ws, size_t ws_size,
                              hipStream_t stream) {
    const float* x      = (const float*)d_in[0];
    const float* weight = (const float*)d_in[1];
    const float* bias   = (const float*)d_in[2];
    const float* gamma  = (const float*)d_in[3];
    const float* beta   = (const float*)d_in[4];
    const float* mean   = (const float*)d_in[5];
    const float* var    = (const float*)d_in[6];
    float* out = (float*)d_out;

    uint8_t* ws = (uint8_t*)d_ws;
    size_t need = ACT_BYTES + WI8_BYTES + 1024;

    if (ws_size >= need) {
        uint8_t*  act  = ws;
        uint32_t* wI8  = (uint32_t*)(ws + ACT_BYTES);
        float*    invG = (float*)(ws + ACT_BYTES + WI8_BYTES);
        float*    b0G  = invG + P_;
        pack_act<<<N_ * ACT_NROWS, 256, 0, stream>>>(x, act);
        wpack_kernel<<<144, 256, 0, stream>>>(weight, bias, gamma, beta, mean, var, wI8, invG, b0G);
        bconv_dma<<<32 * 28, 256, 0, stream>>>((const uint4*)wI8, invG, b0G, act, x, out);
    } else {
        uint32_t* wI8  = (uint32_t*)ws;
        float*    invG = (float*)(ws + WI8_BYTES);
        float*    b0G  = invG + P_;
        wpack_kernel<<<144, 256, 0, stream>>>(weight, bias, gamma, beta, mean, var, wI8, invG, b0G);
        bconv_fused<<<32 * 28, 256, 0, stream>>>((const uint4*)wI8, invG, b0G, x, out);
    }
}